// Round 1
// 709.933 us; speedup vs baseline: 1.0441x; 1.0441x over previous
//
#include <hip/hip_runtime.h>
#include <math.h>

#define TAU_INV (1.0f / 1000000.0f)
#define BIAS_F 1.0f

// ---------------------------------------------------------------------------
// K0: inclusive scan of per-user edge counts -> offsets[0..B]
// Shuffle-based wave scan (2 barriers instead of 20).
// ---------------------------------------------------------------------------
__global__ void scan_counts(const int* __restrict__ counts,
                            int* __restrict__ offsets, int B) {
    __shared__ int wsums[16];
    int t = threadIdx.x;
    int lane = t & 63, w = t >> 6;
    int v = (t < B) ? counts[t] : 0;
    int s = v;
#pragma unroll
    for (int d = 1; d < 64; d <<= 1) {
        int n = __shfl_up(s, d);
        if (lane >= d) s += n;
    }
    if (lane == 63) wsums[w] = s;
    __syncthreads();
    if (t < 16) {
        int x = wsums[t];
#pragma unroll
        for (int d = 1; d < 16; d <<= 1) {
            int n = __shfl_up(x, d);
            if (t >= d) x += n;
        }
        wsums[t] = x;
    }
    __syncthreads();
    if (w > 0) s += wsums[w - 1];
    if (t < B) offsets[t + 1] = s;
    if (t == 0) offsets[0] = 0;
}

// ---------------------------------------------------------------------------
// K1: edge -> (user, col-within-user) maps
// ---------------------------------------------------------------------------
__global__ void fill_edges(const int* __restrict__ offsets,
                           int* __restrict__ euser, int* __restrict__ ecol) {
    int b = blockIdx.x;
    int start = offsets[b];
    int n = offsets[b + 1] - start;
    for (int i = threadIdx.x; i < n; i += blockDim.x) {
        euser[start + i] = b;
        ecol[start + i] = i;
    }
}

// ---------------------------------------------------------------------------
// K2: Mt[j][d] = sum_f W_beta[f][d] * W_friend[f][j]   ([128,64], transposed)
// ---------------------------------------------------------------------------
__global__ void compute_Mt(const float* __restrict__ Wf,   // [64,128]
                           const float* __restrict__ Wb,   // [64,64]
                           float* __restrict__ Mt) {       // [128,64]
    int idx = blockIdx.x * 256 + threadIdx.x;  // 8192 outputs
    int d = idx & 63;
    int j = idx >> 6;
    float acc = 0.f;
#pragma unroll
    for (int f = 0; f < 64; ++f)
        acc += Wb[f * 64 + d] * Wf[f * 128 + j];
    Mt[j * 64 + d] = acc;
}

// ---------------------------------------------------------------------------
// K3: SU[b][d] = sum_{j<64} Mt[j][d] * self_x[b][j]   (per-user self part)
// ---------------------------------------------------------------------------
__global__ void compute_SU(const float* __restrict__ Mt,
                           const float* __restrict__ selfx,  // [B,64]
                           float* __restrict__ SU) {         // [B,64]
    int idx = blockIdx.x * 256 + threadIdx.x;
    int d = idx & 63;
    int b = idx >> 6;
    float acc = 0.f;
#pragma unroll 8
    for (int j = 0; j < 64; ++j)
        acc += Mt[j * 64 + d] * selfx[b * 64 + j];
    SU[b * 64 + d] = acc;
}

// ---------------------------------------------------------------------------
// K4: main streaming kernel — one block per edge.
//   NEW: mask-gated row skipping. w[c] = softplus(score)*temporal*mask, and
//   temporal=exp(1-t/TAU) is never 0 — only mask gates a row. ~50% of the
//   256B common_x rows are dead. Wave 1 loads ct/mask, builds the compacted
//   active-c list via __ballot + popcount prefix; the dot loop then touches
//   only active rows (each 16-lane group loads one contiguous 256B row).
//   This halves the dominant HBM stream (512 MiB -> ~268 MB per pass).
//   Wave 0 builds v[d] = SU[u][d] + Mt2·fx[e] concurrently.
// ---------------------------------------------------------------------------
__global__ __launch_bounds__(256) void friendship_main(
    const float* __restrict__ cx,   // [E,64,64]
    const float* __restrict__ ct,   // [E,64]
    const int*   __restrict__ mask, // [E,64]
    const float* __restrict__ fx,   // [E,64]
    const float* __restrict__ Mt,   // [128,64]
    const float* __restrict__ SU,   // [B,64]
    const int*   __restrict__ euser,
    const int*   __restrict__ ecol,
    float* __restrict__ out, int maxn) {
    int e = blockIdx.x;
    int t = threadIdx.x;
    __shared__ float vsh[64];
    __shared__ float wt[64];    // compacted temporal weights (active c's)
    __shared__ int   actc[64];  // compacted active c indices
    __shared__ int   nact_sh;
    __shared__ float wsum[4];

    int u = euser[e];
    int col = ecol[e];

    if (t < 64) {
        // wave 0: v[d] = SU[u][d] + sum_j Mt2[j][d] * fx[e][j]
        float acc = SU[u * 64 + t];
        const float* f = fx + (size_t)e * 64;
        const float* m2 = Mt + 64 * 64 + t;
#pragma unroll 8
        for (int j = 0; j < 64; ++j)
            acc += m2[j * 64] * f[j];
        vsh[t] = acc;
    } else if (t < 128) {
        // wave 1 (exactly one full wave, lane == c): temporal*mask weight,
        // then stream-compact the active c's.
        int c = t - 64;
        float tm = ct[e * 64 + c];
        int m = mask[e * 64 + c];
        float tw = m ? expf(BIAS_F - tm * TAU_INV) : 0.f;
        unsigned long long act = __ballot(tw != 0.f);
        if (tw != 0.f) {
            int pos = __popcll(act & ((1ull << c) - 1));
            actc[pos] = c;
            wt[pos] = tw;
        }
        if (c == 0) nact_sh = __popcll(act);
    }
    __syncthreads();

    // each thread's 4 fixed v components (d = (t&15)*4 .. +3)
    float4 v = *(const float4*)&vsh[(t & 15) * 4];
    int nact = nact_sh;           // block-uniform trip count
    float acc = 0.f;
    const float* xe = cx + (size_t)e * 4096;
    int g = t >> 4;               // 16 groups of 16 lanes; group g -> row actc[i]
    for (int i = g; i < nact; i += 16) {
        int c = actc[i];
        float4 x = *(const float4*)&xe[c * 64 + (t & 15) * 4];
        float p = x.x * v.x + x.y * v.y + x.z * v.z + x.w * v.w;
        // reduce the 64-element dot across the 16-lane group
        p += __shfl_xor(p, 1);
        p += __shfl_xor(p, 2);
        p += __shfl_xor(p, 4);
        p += __shfl_xor(p, 8);
        if ((t & 15) == 0) {
            // softplus(p) = max(p,0) + log1p(exp(-|p|))
            float sp = fmaxf(p, 0.f) + log1pf(expf(-fabsf(p)));
            acc += sp * wt[i];
        }
    }
    // sum the 16 group-leaders: lanes 0,16,32,48 within each wave, then LDS
    acc += __shfl_xor(acc, 16);
    acc += __shfl_xor(acc, 32);
    if ((t & 63) == 0) wsum[t >> 6] = acc;
    __syncthreads();
    if (t == 0)
        out[(size_t)u * maxn + col] = wsum[0] + wsum[1] + wsum[2] + wsum[3];
}

// ---------------------------------------------------------------------------
extern "C" void kernel_launch(void* const* d_in, const int* in_sizes, int n_in,
                              void* d_out, int out_size, void* d_ws,
                              size_t ws_size, hipStream_t stream) {
    const float* self_x      = (const float*)d_in[0];  // [B,64]
    const float* common_x    = (const float*)d_in[1];  // [E,64,64]
    const float* common_time = (const float*)d_in[2];  // [E,64]
    const int*   common_mask = (const int*)d_in[3];    // [E,64]
    const float* friend_x    = (const float*)d_in[4];  // [E,64]
    const int*   counts      = (const int*)d_in[5];    // [B]
    const float* W_friend    = (const float*)d_in[6];  // [64,128]
    const float* W_beta      = (const float*)d_in[7];  // [64,64]
    float* out = (float*)d_out;

    const int B = in_sizes[5];
    const int E = in_sizes[4] / 64;
    const int maxn = out_size / B;

    // workspace layout
    char* ws = (char*)d_ws;
    int*   offsets = (int*)ws;                                   // (B+1) ints
    int*   euser   = (int*)(ws + 8192);                          // E ints
    int*   ecol    = (int*)(ws + 8192 + (size_t)E * 4);          // E ints
    float* Mt      = (float*)(ws + 8192 + (size_t)E * 8);        // 128*64 f32
    float* SU      = (float*)(ws + 8192 + (size_t)E * 8 + 32768);// B*64 f32

    // d_out is poisoned before every timed launch — zero it (memset node is
    // graph-capturable)
    hipMemsetAsync(d_out, 0, (size_t)out_size * sizeof(float), stream);

    hipLaunchKernelGGL(scan_counts, dim3(1), dim3(1024), 0, stream,
                       counts, offsets, B);
    hipLaunchKernelGGL(fill_edges, dim3(B), dim3(64), 0, stream,
                       offsets, euser, ecol);
    hipLaunchKernelGGL(compute_Mt, dim3(32), dim3(256), 0, stream,
                       W_friend, W_beta, Mt);
    hipLaunchKernelGGL(compute_SU, dim3((B * 64) / 256), dim3(256), 0, stream,
                       Mt, self_x, SU);
    hipLaunchKernelGGL(friendship_main, dim3(E), dim3(256), 0, stream,
                       common_x, common_time, common_mask, friend_x,
                       Mt, SU, euser, ecol, out, maxn);
}